// Round 9
// baseline (542.110 us; speedup 1.0000x reference)
//
#include <hip/hip_runtime.h>
#include <hip/hip_bf16.h>
#include <hip/hip_cooperative_groups.h>

namespace cg = cooperative_groups;

#define N_NODES 50000
#define N_EDGES 800000
#define DIM 64
#define NHEAD 2
#define HD 128     // NHEAD * DIM
#define NCOL 448   // 128 q + 128 k + 128 vc + 64 skipc
#define NPAD 50048 // xb rows padded to multiple of 64
#define SCAN_B 196 // ceil(50000/256)

typedef short bf16x8 __attribute__((ext_vector_type(8)));
typedef float f32x16 __attribute__((ext_vector_type(16)));

__device__ __forceinline__ float bflo(unsigned u) { return __uint_as_float(u << 16); }
__device__ __forceinline__ float bfhi(unsigned u) { return __uint_as_float(u & 0xffff0000u); }
__device__ __forceinline__ unsigned short f2bf(float f) {
    unsigned u = __float_as_uint(f);
    unsigned r = (u + 0x7fffu + ((u >> 16) & 1u)) >> 16;   // RNE
    return (unsigned short)r;
}

// ---------- shared device helpers (used by fused AND fallback paths) ----------

// one element of the folded combined weight  WallT[448][64] + ball[448]
__device__ __forceinline__ void prep_one(
    int gid,
    const float* __restrict__ Wq, const float* __restrict__ bq,
    const float* __restrict__ Wk, const float* __restrict__ bk,
    const float* __restrict__ Wv, const float* __restrict__ bv,
    const float* __restrict__ Wskip, const float* __restrict__ bskip,
    const float* __restrict__ Wc, const float* __restrict__ bc,
    unsigned short* __restrict__ WallT, float* __restrict__ ball)
{
    const int j = gid >> 6;   // output column 0..447
    const int d = gid & 63;   // k index
    float w, bb;
    if (j < 128) {
        w = Wq[d * HD + j] * 0.125f;
        bb = bq[j] * 0.125f;
    } else if (j < 256) {
        int jj = j - 128;
        w = Wk[d * HD + jj];
        bb = bk[jj];
    } else if (j < 384) {
        int jj = j - 256;
        int h = jj >> 6, jc = jj & 63;
        float s = 0.f, sb = 0.f;
        for (int c = 0; c < 64; c++) {
            float wc = Wc[(h * 64 + c) * DIM + jc];
            s  += Wv[d * HD + h * 64 + c] * wc;
            sb += bv[h * 64 + c] * wc;
        }
        w = s; bb = sb;
    } else {
        int jj = j - 384;
        float s = 0.f, sb = bc[jj];
        for (int c = 0; c < HD; c++) {
            float wc = Wc[c * DIM + jj];
            s  += Wskip[d * HD + c] * wc;
            sb += bskip[c] * wc;
        }
        w = s; bb = sb;
    }
    WallT[gid] = f2bf(w);
    if (d == 0) ball[j] = bb;
}

// one 64-node tile of the MFMA projection GEMM [NPAD x 64] @ [64 x 448]
// C/D mapping: col=lane&31, row=(reg&3)+8*(reg>>2)+4*(lane>>5)
__device__ __forceinline__ void proj_tile(
    int bb, int w, int lane,
    const unsigned short* __restrict__ xb, const unsigned short* __restrict__ WallT,
    const float* __restrict__ ball,
    float* __restrict__ q, unsigned short* __restrict__ kv, float* __restrict__ skipc)
{
    const int col = lane & 31;
    const int khalf = lane >> 5;
    const int n0 = bb * 64 + (w >> 1) * 32;
    const int ct0 = (w & 1) * 7;
    const int rowbase = 4 * khalf;
    bf16x8 afrag[4];
    const unsigned short* ap = xb + (size_t)(n0 + col) * 64 + khalf * 8;
#pragma unroll
    for (int kk = 0; kk < 4; kk++)
        afrag[kk] = *((const bf16x8*)(ap + kk * 16));
    for (int tt = 0; tt < 7; tt++) {
        const int gc = (ct0 + tt) * 32 + col;
        const float b = ball[gc];
        f32x16 acc;
#pragma unroll
        for (int r = 0; r < 16; r++) acc[r] = b;
        const unsigned short* bp = WallT + (size_t)gc * 64 + khalf * 8;
#pragma unroll
        for (int kk = 0; kk < 4; kk++) {
            bf16x8 bfrag = *((const bf16x8*)(bp + kk * 16));
            acc = __builtin_amdgcn_mfma_f32_32x32x16_bf16(afrag[kk], bfrag, acc, 0, 0, 0);
        }
        if (gc < 128) {
#pragma unroll
            for (int r = 0; r < 16; r++) {
                int node = n0 + (r & 3) + 8 * (r >> 2) + rowbase;
                if (node < N_NODES) q[(size_t)node * HD + gc] = acc[r];
            }
        } else if (gc < 256) {
#pragma unroll
            for (int r = 0; r < 16; r++) {
                int node = n0 + (r & 3) + 8 * (r >> 2) + rowbase;
                if (node < N_NODES) kv[(size_t)node * 256 + (gc - 128)] = f2bf(acc[r]);
            }
        } else if (gc < 384) {
#pragma unroll
            for (int r = 0; r < 16; r++) {
                int node = n0 + (r & 3) + 8 * (r >> 2) + rowbase;
                if (node < N_NODES) kv[(size_t)node * 256 + 128 + (gc - 256)] = f2bf(acc[r]);
            }
        } else {
#pragma unroll
            for (int r = 0; r < 16; r++) {
                int node = n0 + (r & 3) + 8 * (r >> 2) + rowbase;
                if (node < N_NODES) skipc[(size_t)node * DIM + (gc - 384)] = acc[r];
            }
        }
    }
}

// full attention + skip + stats for one dst node (one wave; 8 edge-groups x 8 lanes)
__device__ __forceinline__ void attn_node(
    int n, int lane,
    const float* __restrict__ q, const unsigned short* __restrict__ kv,
    const float* __restrict__ skipc,
    const int* __restrict__ rowstart, const int* __restrict__ deg,
    const int* __restrict__ elist,
    float* __restrict__ out, float* __restrict__ parts)
{
    const int g = lane >> 3;
    const int j = lane & 7;
    const float4* qp = (const float4*)(q + (size_t)n * HD);
    const float4 qa = qp[2 * j],      qb = qp[2 * j + 1];
    const float4 qc = qp[16 + 2 * j], qd = qp[17 + 2 * j];
    float acc0[8], acc1[8];
#pragma unroll
    for (int i = 0; i < 8; i++) { acc0[i] = 0.f; acc1[i] = 0.f; }
    float l0 = 0.f, l1 = 0.f;
    const int start = rowstart[n];
    const int end = start + deg[n];
    for (int b0 = start; b0 < end; b0 += 8) {
        int idx = b0 + g;
        bool valid = idx < end;
        int s = elist[valid ? idx : start];
        const uint4* kp = (const uint4*)(kv + (size_t)s * 256);
        uint4 K0 = kp[j], K1 = kp[8 + j];
        uint4 V0 = kp[16 + j], V1 = kp[24 + j];
        float p0 = qa.x * bflo(K0.x) + qa.y * bfhi(K0.x)
                 + qa.z * bflo(K0.y) + qa.w * bfhi(K0.y)
                 + qb.x * bflo(K0.z) + qb.y * bfhi(K0.z)
                 + qb.z * bflo(K0.w) + qb.w * bfhi(K0.w);
        float p1 = qc.x * bflo(K1.x) + qc.y * bfhi(K1.x)
                 + qc.z * bflo(K1.y) + qc.w * bfhi(K1.y)
                 + qd.x * bflo(K1.z) + qd.y * bfhi(K1.z)
                 + qd.z * bflo(K1.w) + qd.w * bfhi(K1.w);
#pragma unroll
        for (int off = 1; off < 8; off <<= 1) {
            p0 += __shfl_xor(p0, off, 64);
            p1 += __shfl_xor(p1, off, 64);
        }
        float w0 = valid ? __expf(p0) : 0.f;
        float w1 = valid ? __expf(p1) : 0.f;
        l0 += w0; l1 += w1;
        acc0[0] += w0 * bflo(V0.x); acc0[1] += w0 * bfhi(V0.x);
        acc0[2] += w0 * bflo(V0.y); acc0[3] += w0 * bfhi(V0.y);
        acc0[4] += w0 * bflo(V0.z); acc0[5] += w0 * bfhi(V0.z);
        acc0[6] += w0 * bflo(V0.w); acc0[7] += w0 * bfhi(V0.w);
        acc1[0] += w1 * bflo(V1.x); acc1[1] += w1 * bfhi(V1.x);
        acc1[2] += w1 * bflo(V1.y); acc1[3] += w1 * bfhi(V1.y);
        acc1[4] += w1 * bflo(V1.z); acc1[5] += w1 * bfhi(V1.z);
        acc1[6] += w1 * bflo(V1.w); acc1[7] += w1 * bfhi(V1.w);
    }
#pragma unroll
    for (int off = 8; off < 64; off <<= 1) {
        l0 += __shfl_xor(l0, off, 64);
        l1 += __shfl_xor(l1, off, 64);
#pragma unroll
        for (int i = 0; i < 8; i++) {
            acc0[i] += __shfl_xor(acc0[i], off, 64);
            acc1[i] += __shfl_xor(acc1[i], off, 64);
        }
    }
    if (g == 0) {
        float inv0 = 1.f / (l0 + 1e-16f), inv1 = 1.f / (l1 + 1e-16f);
        const float4* sk = (const float4*)(skipc + (size_t)n * DIM);
        float4 sa = sk[2 * j], sb = sk[2 * j + 1];
        float o[8];
        o[0] = acc0[0] * inv0 + acc1[0] * inv1 + sa.x;
        o[1] = acc0[1] * inv0 + acc1[1] * inv1 + sa.y;
        o[2] = acc0[2] * inv0 + acc1[2] * inv1 + sa.z;
        o[3] = acc0[3] * inv0 + acc1[3] * inv1 + sa.w;
        o[4] = acc0[4] * inv0 + acc1[4] * inv1 + sb.x;
        o[5] = acc0[5] * inv0 + acc1[5] * inv1 + sb.y;
        o[6] = acc0[6] * inv0 + acc1[6] * inv1 + sb.z;
        o[7] = acc0[7] * inv0 + acc1[7] * inv1 + sb.w;
        float4 r0 = {o[0], o[1], o[2], o[3]}, r1 = {o[4], o[5], o[6], o[7]};
        float4* op = (float4*)(out + (size_t)n * DIM);
        op[2 * j] = r0; op[2 * j + 1] = r1;
        float s_ = 0.f, ss = 0.f;
#pragma unroll
        for (int i = 0; i < 8; i++) { s_ += o[i]; ss += o[i] * o[i]; }
#pragma unroll
        for (int off = 1; off < 8; off <<= 1) {
            s_ += __shfl_xor(s_, off, 64);
            ss += __shfl_xor(ss, off, 64);
        }
        if (j == 0) { parts[n * 2 + 0] = s_; parts[n * 2 + 1] = ss; }
    }
}

// ================= fused cooperative kernel (gridDim-agnostic) =================
__global__ __launch_bounds__(256) void k_fused(
    const float* __restrict__ x, const int* __restrict__ ei,
    const float* __restrict__ Wq, const float* __restrict__ bq,
    const float* __restrict__ Wk, const float* __restrict__ bk,
    const float* __restrict__ Wv, const float* __restrict__ bv,
    const float* __restrict__ Wskip, const float* __restrict__ bskip,
    const float* __restrict__ Wc, const float* __restrict__ bc,
    const float* __restrict__ gamma, const float* __restrict__ beta,
    float* __restrict__ out,
    float* __restrict__ q, unsigned short* __restrict__ kv,
    float* __restrict__ skipc, unsigned short* __restrict__ xb,
    unsigned short* __restrict__ WallT, float* __restrict__ ball,
    int* __restrict__ deg, int* __restrict__ rowstart, int* __restrict__ bsum,
    int* __restrict__ rank, int* __restrict__ elist,
    float* __restrict__ parts, double* __restrict__ stats)
{
    cg::grid_group grid = cg::this_grid();
    const int t = threadIdx.x;
    const int b = blockIdx.x;
    const int gid = b * 256 + t;
    const int GT = gridDim.x * 256;
    __shared__ int sd4[4];
    __shared__ int swv[4];
    __shared__ int sd[256];
    __shared__ double sdd[8];

    // S0: weight prep + zero deg + zero stats
    if (gid == 0) { stats[0] = 0.0; stats[1] = 0.0; }
    for (int i = gid; i < N_NODES; i += GT) deg[i] = 0;
    for (int i = gid; i < NCOL * 64; i += GT)
        prep_one(i, Wq, bq, Wk, bk, Wv, bv, Wskip, bskip, Wc, bc, WallT, ball);
    grid.sync();

    // S1: cast x -> bf16 (800000 float4 == N*64/4) + degree histogram with rank
    for (int i = gid; i < N_EDGES; i += GT) {
        rank[i] = atomicAdd(&deg[ei[N_EDGES + i]], 1);
        float4 xv = ((const float4*)x)[i];
        ushort4 o;
        o.x = f2bf(xv.x); o.y = f2bf(xv.y); o.z = f2bf(xv.z); o.w = f2bf(xv.w);
        ((ushort4*)xb)[i] = o;
    }
    grid.sync();

    // S2a: per-256-node chunk sums
    for (int sb = b; sb < SCAN_B; sb += gridDim.x) {
        int idx = sb * 256 + t;
        int d = (idx < N_NODES) ? deg[idx] : 0;
        int s = d;
#pragma unroll
        for (int off = 32; off > 0; off >>= 1) s += __shfl_down(s, off);
        if ((t & 63) == 0) sd4[t >> 6] = s;
        __syncthreads();
        if (t == 0) bsum[sb] = sd4[0] + sd4[1] + sd4[2] + sd4[3];
        __syncthreads();
    }
    grid.sync();

    // S2b: chunk offset + local exclusive scan -> rowstart
    for (int sb = b; sb < SCAN_B; sb += gridDim.x) {
        int v = (t < sb) ? bsum[t] : 0;   // sb <= 195 < 256
#pragma unroll
        for (int off = 32; off > 0; off >>= 1) v += __shfl_down(v, off);
        if ((t & 63) == 0) swv[t >> 6] = v;
        int idx = sb * 256 + t;
        int d = (idx < N_NODES) ? deg[idx] : 0;
        sd[t] = d;
        __syncthreads();
        int base = swv[0] + swv[1] + swv[2] + swv[3];
        for (int off = 1; off < 256; off <<= 1) {
            int add = (t >= off) ? sd[t - off] : 0;
            __syncthreads();
            sd[t] += add;
            __syncthreads();
        }
        if (idx < N_NODES) rowstart[idx] = base + sd[t] - d;
        __syncthreads();
    }
    grid.sync();

    // S3: fill elist (atomic-free)  +  S4: MFMA projection GEMM
    for (int i = gid; i < N_EDGES; i += GT) {
        int d = ei[N_EDGES + i];
        elist[rowstart[d] + rank[i]] = ei[i];
    }
    {
        const int w = t >> 6;
        const int lane = t & 63;
        for (int bb = b; bb < NPAD / 64; bb += gridDim.x)
            proj_tile(bb, w, lane, xb, WallT, ball, q, kv, skipc);
    }
    grid.sync();

    // S5: attention (persistent waves)
    {
        const int w = t >> 6;
        const int lane = t & 63;
        const int nwaves = gridDim.x * 4;
        for (int n = b * 4 + w; n < N_NODES; n += nwaves)
            attn_node(n, lane, q, kv, skipc, rowstart, deg, elist, out, parts);
    }
    grid.sync();

    // S6: reduce parts -> stats (first 64 blocks)
    if (b < 64) {
        double s = 0.0, ss = 0.0;
        for (int i = b * 256 + t; i < N_NODES; i += 64 * 256) {
            s  += (double)parts[i * 2 + 0];
            ss += (double)parts[i * 2 + 1];
        }
#pragma unroll
        for (int off = 32; off > 0; off >>= 1) {
            s  += __shfl_down(s, off);
            ss += __shfl_down(ss, off);
        }
        int wave = t >> 6;
        if ((t & 63) == 0) { sdd[wave * 2] = s; sdd[wave * 2 + 1] = ss; }
        __syncthreads();
        if (t == 0) {
            double S = 0.0, SS = 0.0;
            for (int w2 = 0; w2 < 4; w2++) { S += sdd[w2 * 2]; SS += sdd[w2 * 2 + 1]; }
            atomicAdd(&stats[0], S);
            atomicAdd(&stats[1], SS);
        }
    }
    grid.sync();

    // S7: graph layernorm in place on out
    {
        const double cnt = (double)N_NODES * (double)DIM;
        double mean = stats[0] / cnt;
        double var  = stats[1] / cnt - mean * mean;
        if (var < 0.0) var = 0.0;
        float mf = (float)mean;
        float inv = 1.0f / ((float)sqrt(var) + 1e-5f);
        for (int i = gid; i < N_NODES * DIM / 4; i += GT) {
            float4 v = ((const float4*)out)[i];
            float4 gv = ((const float4*)gamma)[i & 15];
            float4 bv2 = ((const float4*)beta)[i & 15];
            v.x = (v.x - mf) * inv * gv.x + bv2.x;
            v.y = (v.y - mf) * inv * gv.y + bv2.y;
            v.z = (v.z - mf) * inv * gv.z + bv2.z;
            v.w = (v.w - mf) * inv * gv.w + bv2.w;
            ((float4*)out)[i] = v;
        }
    }
}

// ================= fallback multi-kernel path (round-6 proven) =================
__global__ __launch_bounds__(256) void k_prep(
    const float* __restrict__ Wq, const float* __restrict__ bq,
    const float* __restrict__ Wk, const float* __restrict__ bk,
    const float* __restrict__ Wv, const float* __restrict__ bv,
    const float* __restrict__ Wskip, const float* __restrict__ bskip,
    const float* __restrict__ Wc, const float* __restrict__ bc,
    unsigned short* __restrict__ WallT, float* __restrict__ ball,
    double* __restrict__ stats)
{
    int gid = blockIdx.x * 256 + threadIdx.x;
    if (gid == 0) { stats[0] = 0.0; stats[1] = 0.0; }
    if (gid < NCOL * 64)
        prep_one(gid, Wq, bq, Wk, bk, Wv, bv, Wskip, bskip, Wc, bc, WallT, ball);
}

__global__ __launch_bounds__(256) void k_cast(
    const float* __restrict__ x, const int* __restrict__ ei,
    unsigned short* __restrict__ xb, int* __restrict__ deg, int* __restrict__ rank)
{
    int gid = blockIdx.x * 256 + threadIdx.x;
    rank[gid] = atomicAdd(&deg[ei[N_EDGES + gid]], 1);
    float4 xv = ((const float4*)x)[gid];
    ushort4 o;
    o.x = f2bf(xv.x); o.y = f2bf(xv.y); o.z = f2bf(xv.z); o.w = f2bf(xv.w);
    ((ushort4*)xb)[gid] = o;
}

__global__ __launch_bounds__(256) void k_scanA(
    const int* __restrict__ deg, int* __restrict__ bsum)
{
    int idx = blockIdx.x * 256 + threadIdx.x;
    int d = (idx < N_NODES) ? deg[idx] : 0;
    int s = d;
#pragma unroll
    for (int off = 32; off > 0; off >>= 1) s += __shfl_down(s, off);
    __shared__ int sd4[4];
    if ((threadIdx.x & 63) == 0) sd4[threadIdx.x >> 6] = s;
    __syncthreads();
    if (threadIdx.x == 0) bsum[blockIdx.x] = sd4[0] + sd4[1] + sd4[2] + sd4[3];
}

__global__ __launch_bounds__(256) void k_scanB(
    const int* __restrict__ deg, const int* __restrict__ bsum,
    int* __restrict__ rowstart)
{
    const int t = threadIdx.x;
    const int b = blockIdx.x;
    int v = (t < b) ? bsum[t] : 0;
#pragma unroll
    for (int off = 32; off > 0; off >>= 1) v += __shfl_down(v, off);
    __shared__ int swv[4];
    if ((t & 63) == 0) swv[t >> 6] = v;
    __shared__ int sd[256];
    int idx = b * 256 + t;
    int d = (idx < N_NODES) ? deg[idx] : 0;
    sd[t] = d;
    __syncthreads();
    int base = swv[0] + swv[1] + swv[2] + swv[3];
    for (int off = 1; off < 256; off <<= 1) {
        int add = (t >= off) ? sd[t - off] : 0;
        __syncthreads();
        sd[t] += add;
        __syncthreads();
    }
    if (idx < N_NODES) rowstart[idx] = base + sd[t] - d;
}

__global__ __launch_bounds__(256) void k_fill(
    const int* __restrict__ ei, const int* __restrict__ rowstart,
    const int* __restrict__ rank, int* __restrict__ elist)
{
    int i = blockIdx.x * 256 + threadIdx.x;
    int d = ei[N_EDGES + i];
    elist[rowstart[d] + rank[i]] = ei[i];
}

__global__ __launch_bounds__(256) void k_proj_sep(
    const unsigned short* __restrict__ xb, const unsigned short* __restrict__ WallT,
    const float* __restrict__ ball,
    float* __restrict__ q, unsigned short* __restrict__ kv, float* __restrict__ skipc)
{
    proj_tile(blockIdx.x, threadIdx.x >> 6, threadIdx.x & 63, xb, WallT, ball, q, kv, skipc);
}

__global__ __launch_bounds__(256) void k_attn_sep(
    const float* __restrict__ q, const unsigned short* __restrict__ kv,
    const float* __restrict__ skipc,
    const int* __restrict__ rowstart, const int* __restrict__ deg,
    const int* __restrict__ elist,
    float* __restrict__ out, float* __restrict__ parts)
{
    int n = blockIdx.x * 4 + (threadIdx.x >> 6);
    attn_node(n, threadIdx.x & 63, q, kv, skipc, rowstart, deg, elist, out, parts);
}

#define RED_BLOCKS 100
__global__ __launch_bounds__(256) void k_reduce(
    const float* __restrict__ parts, double* __restrict__ stats)
{
    double s = 0.0, ss = 0.0;
    for (int i = blockIdx.x * 256 + threadIdx.x; i < N_NODES; i += RED_BLOCKS * 256) {
        s  += (double)parts[i * 2 + 0];
        ss += (double)parts[i * 2 + 1];
    }
#pragma unroll
    for (int off = 32; off > 0; off >>= 1) {
        s  += __shfl_down(s, off);
        ss += __shfl_down(ss, off);
    }
    __shared__ double sdd[8];
    int wave = threadIdx.x >> 6;
    if ((threadIdx.x & 63) == 0) { sdd[wave * 2] = s; sdd[wave * 2 + 1] = ss; }
    __syncthreads();
    if (threadIdx.x == 0) {
        double S = 0.0, SS = 0.0;
        for (int w = 0; w < 4; w++) { S += sdd[w * 2]; SS += sdd[w * 2 + 1]; }
        atomicAdd(&stats[0], S);
        atomicAdd(&stats[1], SS);
    }
}

__global__ __launch_bounds__(256) void k_norm(
    float* __restrict__ out, const double* __restrict__ stats,
    const float* __restrict__ gamma, const float* __restrict__ beta)
{
    int i = blockIdx.x * 256 + threadIdx.x;
    if (i >= N_NODES * DIM / 4) return;
    const double cnt = (double)N_NODES * (double)DIM;
    double mean = stats[0] / cnt;
    double var  = stats[1] / cnt - mean * mean;
    if (var < 0.0) var = 0.0;
    float mf = (float)mean;
    float inv = 1.0f / ((float)sqrt(var) + 1e-5f);
    float4 v = ((const float4*)out)[i];
    float4 gv = ((const float4*)gamma)[i & 15];
    float4 bv2 = ((const float4*)beta)[i & 15];
    v.x = (v.x - mf) * inv * gv.x + bv2.x;
    v.y = (v.y - mf) * inv * gv.y + bv2.y;
    v.z = (v.z - mf) * inv * gv.z + bv2.z;
    v.w = (v.w - mf) * inv * gv.w + bv2.w;
    ((float4*)out)[i] = v;
}

extern "C" void kernel_launch(void* const* d_in, const int* in_sizes, int n_in,
                              void* d_out, int out_size, void* d_ws, size_t ws_size,
                              hipStream_t stream) {
    const float* x     = (const float*)d_in[0];
    const int*   ei    = (const int*)d_in[1];
    const float* Wq    = (const float*)d_in[2];
    const float* bq    = (const float*)d_in[3];
    const float* Wk    = (const float*)d_in[4];
    const float* bk    = (const float*)d_in[5];
    const float* Wv    = (const float*)d_in[6];
    const float* bv    = (const float*)d_in[7];
    const float* Wsk   = (const float*)d_in[8];
    const float* bsk   = (const float*)d_in[9];
    const float* Wc    = (const float*)d_in[10];
    const float* bc    = (const float*)d_in[11];
    const float* gamma = (const float*)d_in[12];
    const float* beta  = (const float*)d_in[13];
    float* out = (float*)d_out;

    // ws layout
    float* ws = (float*)d_ws;
    const size_t NF = (size_t)N_NODES * HD;               // 6.4M floats
    float* q = ws;                                        // [N,128] f32
    unsigned short* kv = (unsigned short*)(ws + NF);      // [N,256] bf16 (k|vc)
    float* skipc = ws + 2 * NF;                           // [N,64]  f32
    unsigned short* xb = (unsigned short*)(skipc + (size_t)N_NODES * DIM); // [NPAD,64]
    unsigned short* WallT = xb + (size_t)NPAD * 64;       // [448,64] bf16
    float* ball   = (float*)(WallT + NCOL * 64);          // [448]
    int* deg      = (int*)(ball + NCOL);                  // [N]
    int* rowstart = deg + N_NODES;                        // [N]
    int* bsum     = rowstart + N_NODES;                   // [256]
    int* rank     = bsum + 256;                           // [E]
    int* elist    = rank + N_EDGES;                       // [E]
    float* parts  = (float*)(elist + N_EDGES);            // [N,2]
    double* stats = (double*)(parts + (size_t)N_NODES * 2);

    // --- try single fused cooperative kernel at true co-residency ---
    int nb = 0;
    hipError_t qerr = hipOccupancyMaxActiveBlocksPerMultiprocessor(
        &nb, (const void*)k_fused, 256, 0);
    bool coop_ok = false;
    if (qerr == hipSuccess && nb >= 1) {
        int FB = nb * 256;           // 256 CUs on MI355X
        if (FB > 2048) FB = 2048;
        void* args[] = {
            (void*)&x, (void*)&ei, (void*)&Wq, (void*)&bq, (void*)&Wk, (void*)&bk,
            (void*)&Wv, (void*)&bv, (void*)&Wsk, (void*)&bsk, (void*)&Wc, (void*)&bc,
            (void*)&gamma, (void*)&beta, (void*)&out,
            (void*)&q, (void*)&kv, (void*)&skipc, (void*)&xb, (void*)&WallT, (void*)&ball,
            (void*)&deg, (void*)&rowstart, (void*)&bsum, (void*)&rank, (void*)&elist,
            (void*)&parts, (void*)&stats
        };
        hipError_t lerr = hipLaunchCooperativeKernel((const void*)k_fused, dim3(FB),
                                                     dim3(256), args, 0, stream);
        coop_ok = (lerr == hipSuccess);
    }
    if (coop_ok) return;

    // --- fallback: proven multi-kernel pipeline ---
    hipMemsetAsync(deg, 0, N_NODES * sizeof(int), stream);
    hipLaunchKernelGGL(k_prep, dim3((NCOL * 64 + 255) / 256), dim3(256), 0, stream,
                       Wq, bq, Wk, bk, Wv, bv, Wsk, bsk, Wc, bc, WallT, ball, stats);
    hipLaunchKernelGGL(k_cast, dim3(N_EDGES / 256), dim3(256), 0, stream,
                       x, ei, xb, deg, rank);
    hipLaunchKernelGGL(k_scanA, dim3(SCAN_B), dim3(256), 0, stream, deg, bsum);
    hipLaunchKernelGGL(k_scanB, dim3(SCAN_B), dim3(256), 0, stream, deg, bsum, rowstart);
    hipLaunchKernelGGL(k_fill, dim3(N_EDGES / 256), dim3(256), 0, stream,
                       ei, rowstart, rank, elist);
    hipLaunchKernelGGL(k_proj_sep, dim3(NPAD / 64), dim3(256), 0, stream,
                       xb, WallT, ball, q, kv, skipc);
    hipLaunchKernelGGL(k_attn_sep, dim3(N_NODES / 4), dim3(256), 0, stream,
                       q, kv, skipc, rowstart, deg, elist, out, parts);
    hipLaunchKernelGGL(k_reduce, dim3(RED_BLOCKS), dim3(256), 0, stream, parts, stats);
    hipLaunchKernelGGL(k_norm, dim3(N_NODES * DIM / 4 / 256 + 1), dim3(256), 0, stream,
                       out, stats, gamma, beta);
}

// Round 10
// 230.415 us; speedup vs baseline: 2.3528x; 2.3528x over previous
//
#include <hip/hip_runtime.h>
#include <hip/hip_bf16.h>

#define N_NODES 50000
#define N_EDGES 800000
#define DIM 64
#define NHEAD 2
#define HD 128     // NHEAD * DIM
#define NCOL 448   // 128 q + 128 k + 128 vc + 64 skipc
#define NPAD 50048 // xb rows padded to multiple of 64
#define SCAN_B 196 // ceil(50000/256)

#define PREP_B 112 // 448*64/256
#define CAST_B 3125 // 800000/256
#define PROJ_B 782 // NPAD/64
#define FILL_B 3125

typedef short bf16x8 __attribute__((ext_vector_type(8)));
typedef float f32x16 __attribute__((ext_vector_type(16)));

__device__ __forceinline__ float bflo(unsigned u) { return __uint_as_float(u << 16); }
__device__ __forceinline__ float bfhi(unsigned u) { return __uint_as_float(u & 0xffff0000u); }
__device__ __forceinline__ unsigned short f2bf(float f) {
    unsigned u = __float_as_uint(f);
    unsigned r = (u + 0x7fffu + ((u >> 16) & 1u)) >> 16;   // RNE
    return (unsigned short)r;
}

// ---------------- merged: folded-weight prep ∥ x-cast + degree histogram ----------------
// blocks [0,PREP_B): WallT[448][64] + ball[448]
// blocks [PREP_B, PREP_B+CAST_B): cast 4 x-floats -> bf16 and count 1 edge (rank = old)
__global__ __launch_bounds__(256) void k_pc(
    const float* __restrict__ x, const int* __restrict__ ei,
    const float* __restrict__ Wq, const float* __restrict__ bq,
    const float* __restrict__ Wk, const float* __restrict__ bk,
    const float* __restrict__ Wv, const float* __restrict__ bv,
    const float* __restrict__ Wskip, const float* __restrict__ bskip,
    const float* __restrict__ Wc, const float* __restrict__ bc,
    unsigned short* __restrict__ WallT, float* __restrict__ ball,
    unsigned short* __restrict__ xb, int* __restrict__ deg, int* __restrict__ rank,
    double* __restrict__ stats)
{
    const int b = blockIdx.x;
    const int t = threadIdx.x;
    if (b < PREP_B) {
        int gid = b * 256 + t;   // 0..28671
        if (gid == 0) { stats[0] = 0.0; stats[1] = 0.0; }
        const int j = gid >> 6;   // output column 0..447
        const int d = gid & 63;   // k index
        float w, bb;
        if (j < 128) {
            w = Wq[d * HD + j] * 0.125f;
            bb = bq[j] * 0.125f;
        } else if (j < 256) {
            int jj = j - 128;
            w = Wk[d * HD + jj];
            bb = bk[jj];
        } else if (j < 384) {
            int jj = j - 256;
            int h = jj >> 6, jc = jj & 63;
            float s = 0.f, sb = 0.f;
            for (int c = 0; c < 64; c++) {
                float wc = Wc[(h * 64 + c) * DIM + jc];
                s  += Wv[d * HD + h * 64 + c] * wc;
                sb += bv[h * 64 + c] * wc;
            }
            w = s; bb = sb;
        } else {
            int jj = j - 384;
            float s = 0.f, sb = bc[jj];
            for (int c = 0; c < HD; c++) {
                float wc = Wc[c * DIM + jj];
                s  += Wskip[d * HD + c] * wc;
                sb += bskip[c] * wc;
            }
            w = s; bb = sb;
        }
        WallT[gid] = f2bf(w);
        if (d == 0) ball[j] = bb;
    } else {
        int gid = (b - PREP_B) * 256 + t;   // 0..799999
        rank[gid] = atomicAdd(&deg[ei[N_EDGES + gid]], 1);
        float4 xv = ((const float4*)x)[gid];
        ushort4 o;
        o.x = f2bf(xv.x); o.y = f2bf(xv.y); o.z = f2bf(xv.z); o.w = f2bf(xv.w);
        ((ushort4*)xb)[gid] = o;
    }
}

// ---------------- scan phase A: per-256-node chunk sums ----------------
__global__ __launch_bounds__(256) void k_scanA(
    const int* __restrict__ deg, int* __restrict__ bsum)
{
    int idx = blockIdx.x * 256 + threadIdx.x;
    int d = (idx < N_NODES) ? deg[idx] : 0;
    int s = d;
#pragma unroll
    for (int off = 32; off > 0; off >>= 1) s += __shfl_down(s, off);
    __shared__ int sd4[4];
    if ((threadIdx.x & 63) == 0) sd4[threadIdx.x >> 6] = s;
    __syncthreads();
    if (threadIdx.x == 0) bsum[blockIdx.x] = sd4[0] + sd4[1] + sd4[2] + sd4[3];
}

// ---------------- scan phase B: chunk offset + local exclusive scan ----------------
__global__ __launch_bounds__(256) void k_scanB(
    const int* __restrict__ deg, const int* __restrict__ bsum,
    int* __restrict__ rowstart)
{
    const int t = threadIdx.x;
    const int b = blockIdx.x;
    int v = (t < b) ? bsum[t] : 0;   // b <= 195 < 256
#pragma unroll
    for (int off = 32; off > 0; off >>= 1) v += __shfl_down(v, off);
    __shared__ int swv[4];
    if ((t & 63) == 0) swv[t >> 6] = v;
    __shared__ int sd[256];
    int idx = b * 256 + t;
    int d = (idx < N_NODES) ? deg[idx] : 0;
    sd[t] = d;
    __syncthreads();
    int base = swv[0] + swv[1] + swv[2] + swv[3];
    for (int off = 1; off < 256; off <<= 1) {
        int add = (t >= off) ? sd[t - off] : 0;
        __syncthreads();
        sd[t] += add;
        __syncthreads();
    }
    if (idx < N_NODES) rowstart[idx] = base + sd[t] - d;
}

// ---------------- merged: MFMA projection GEMM ∥ atomic-free edge fill ----------------
// blocks [0,PROJ_B): one 64-node tile of [NPAD x 64] @ [64 x 448]
//   C/D mapping: col=lane&31, row=(reg&3)+8*(reg>>2)+4*(lane>>5)
// blocks [PROJ_B, PROJ_B+FILL_B): elist[rowstart[d]+rank[e]] = src
__global__ __launch_bounds__(256) void k_fp(
    const unsigned short* __restrict__ xb, const unsigned short* __restrict__ WallT,
    const float* __restrict__ ball,
    float* __restrict__ q, unsigned short* __restrict__ kv, float* __restrict__ skipc,
    const int* __restrict__ ei, const int* __restrict__ rowstart,
    const int* __restrict__ rank, int* __restrict__ elist)
{
    const int blk = blockIdx.x;
    const int t = threadIdx.x;
    if (blk >= PROJ_B) {
        int i = (blk - PROJ_B) * 256 + t;   // 0..799999
        int d = ei[N_EDGES + i];
        elist[rowstart[d] + rank[i]] = ei[i];
        return;
    }
    const int w = t >> 6;
    const int lane = t & 63;
    const int col = lane & 31;
    const int khalf = lane >> 5;
    const int n0 = blk * 64 + (w >> 1) * 32;
    const int ct0 = (w & 1) * 7;
    const int rowbase = 4 * khalf;
    bf16x8 afrag[4];
    const unsigned short* ap = xb + (size_t)(n0 + col) * 64 + khalf * 8;
#pragma unroll
    for (int kk = 0; kk < 4; kk++)
        afrag[kk] = *((const bf16x8*)(ap + kk * 16));
    for (int tt = 0; tt < 7; tt++) {
        const int gc = (ct0 + tt) * 32 + col;
        const float b = ball[gc];
        f32x16 acc;
#pragma unroll
        for (int r = 0; r < 16; r++) acc[r] = b;
        const unsigned short* bp = WallT + (size_t)gc * 64 + khalf * 8;
#pragma unroll
        for (int kk = 0; kk < 4; kk++) {
            bf16x8 bfrag = *((const bf16x8*)(bp + kk * 16));
            acc = __builtin_amdgcn_mfma_f32_32x32x16_bf16(afrag[kk], bfrag, acc, 0, 0, 0);
        }
        if (gc < 128) {
#pragma unroll
            for (int r = 0; r < 16; r++) {
                int node = n0 + (r & 3) + 8 * (r >> 2) + rowbase;
                if (node < N_NODES) q[(size_t)node * HD + gc] = acc[r];
            }
        } else if (gc < 256) {
#pragma unroll
            for (int r = 0; r < 16; r++) {
                int node = n0 + (r & 3) + 8 * (r >> 2) + rowbase;
                if (node < N_NODES) kv[(size_t)node * 256 + (gc - 128)] = f2bf(acc[r]);
            }
        } else if (gc < 384) {
#pragma unroll
            for (int r = 0; r < 16; r++) {
                int node = n0 + (r & 3) + 8 * (r >> 2) + rowbase;
                if (node < N_NODES) kv[(size_t)node * 256 + 128 + (gc - 256)] = f2bf(acc[r]);
            }
        } else {
#pragma unroll
            for (int r = 0; r < 16; r++) {
                int node = n0 + (r & 3) + 8 * (r >> 2) + rowbase;
                if (node < N_NODES) skipc[(size_t)node * DIM + (gc - 384)] = acc[r];
            }
        }
    }
}

// ---------------- fused attention: 8-edge-parallel softmax-aggregate + skipc + stats --
// 4 waves/block, one wave per dst node; 8 groups x 8 lanes, one edge per group/iter.
// kv row (512B): [k h0 | k h1 | vc h0 | vc h1], bf16. q pre-scaled -> no max-subtract.
__global__ __launch_bounds__(256) void k_attn(
    const float* __restrict__ q, const unsigned short* __restrict__ kv,
    const float* __restrict__ skipc,
    const int* __restrict__ rowstart, const int* __restrict__ deg,
    const int* __restrict__ elist,
    float* __restrict__ out, float* __restrict__ parts)
{
    const int w = threadIdx.x >> 6;
    const int lane = threadIdx.x & 63;
    const int g = lane >> 3;
    const int j = lane & 7;
    const int n = blockIdx.x * 4 + w;
    const float4* qp = (const float4*)(q + (size_t)n * HD);
    const float4 qa = qp[2 * j],      qb = qp[2 * j + 1];
    const float4 qc = qp[16 + 2 * j], qd = qp[17 + 2 * j];
    float acc0[8], acc1[8];
#pragma unroll
    for (int i = 0; i < 8; i++) { acc0[i] = 0.f; acc1[i] = 0.f; }
    float l0 = 0.f, l1 = 0.f;
    const int start = rowstart[n];
    const int end = start + deg[n];
    for (int b0 = start; b0 < end; b0 += 8) {
        int idx = b0 + g;
        bool valid = idx < end;
        int s = elist[valid ? idx : start];
        const uint4* kp = (const uint4*)(kv + (size_t)s * 256);
        uint4 K0 = kp[j], K1 = kp[8 + j];
        uint4 V0 = kp[16 + j], V1 = kp[24 + j];
        float p0 = qa.x * bflo(K0.x) + qa.y * bfhi(K0.x)
                 + qa.z * bflo(K0.y) + qa.w * bfhi(K0.y)
                 + qb.x * bflo(K0.z) + qb.y * bfhi(K0.z)
                 + qb.z * bflo(K0.w) + qb.w * bfhi(K0.w);
        float p1 = qc.x * bflo(K1.x) + qc.y * bfhi(K1.x)
                 + qc.z * bflo(K1.y) + qc.w * bfhi(K1.y)
                 + qd.x * bflo(K1.z) + qd.y * bfhi(K1.z)
                 + qd.z * bflo(K1.w) + qd.w * bfhi(K1.w);
#pragma unroll
        for (int off = 1; off < 8; off <<= 1) {
            p0 += __shfl_xor(p0, off, 64);
            p1 += __shfl_xor(p1, off, 64);
        }
        float w0 = valid ? __expf(p0) : 0.f;
        float w1 = valid ? __expf(p1) : 0.f;
        l0 += w0; l1 += w1;
        acc0[0] += w0 * bflo(V0.x); acc0[1] += w0 * bfhi(V0.x);
        acc0[2] += w0 * bflo(V0.y); acc0[3] += w0 * bfhi(V0.y);
        acc0[4] += w0 * bflo(V0.z); acc0[5] += w0 * bfhi(V0.z);
        acc0[6] += w0 * bflo(V0.w); acc0[7] += w0 * bfhi(V0.w);
        acc1[0] += w1 * bflo(V1.x); acc1[1] += w1 * bfhi(V1.x);
        acc1[2] += w1 * bflo(V1.y); acc1[3] += w1 * bfhi(V1.y);
        acc1[4] += w1 * bflo(V1.z); acc1[5] += w1 * bfhi(V1.z);
        acc1[6] += w1 * bflo(V1.w); acc1[7] += w1 * bfhi(V1.w);
    }
#pragma unroll
    for (int off = 8; off < 64; off <<= 1) {
        l0 += __shfl_xor(l0, off, 64);
        l1 += __shfl_xor(l1, off, 64);
#pragma unroll
        for (int i = 0; i < 8; i++) {
            acc0[i] += __shfl_xor(acc0[i], off, 64);
            acc1[i] += __shfl_xor(acc1[i], off, 64);
        }
    }
    if (g == 0) {
        float inv0 = 1.f / (l0 + 1e-16f), inv1 = 1.f / (l1 + 1e-16f);
        const float4* sk = (const float4*)(skipc + (size_t)n * DIM);
        float4 sa = sk[2 * j], sb = sk[2 * j + 1];
        float o[8];
        o[0] = acc0[0] * inv0 + acc1[0] * inv1 + sa.x;
        o[1] = acc0[1] * inv0 + acc1[1] * inv1 + sa.y;
        o[2] = acc0[2] * inv0 + acc1[2] * inv1 + sa.z;
        o[3] = acc0[3] * inv0 + acc1[3] * inv1 + sa.w;
        o[4] = acc0[4] * inv0 + acc1[4] * inv1 + sb.x;
        o[5] = acc0[5] * inv0 + acc1[5] * inv1 + sb.y;
        o[6] = acc0[6] * inv0 + acc1[6] * inv1 + sb.z;
        o[7] = acc0[7] * inv0 + acc1[7] * inv1 + sb.w;
        float4 r0 = {o[0], o[1], o[2], o[3]}, r1 = {o[4], o[5], o[6], o[7]};
        float4* op = (float4*)(out + (size_t)n * DIM);
        op[2 * j] = r0; op[2 * j + 1] = r1;
        float s_ = 0.f, ss = 0.f;
#pragma unroll
        for (int i = 0; i < 8; i++) { s_ += o[i]; ss += o[i] * o[i]; }
#pragma unroll
        for (int off = 1; off < 8; off <<= 1) {
            s_ += __shfl_xor(s_, off, 64);
            ss += __shfl_xor(ss, off, 64);
        }
        if (j == 0) { parts[n * 2 + 0] = s_; parts[n * 2 + 1] = ss; }
    }
}

// ---------------- multi-block reduction of parts -> stats (f64 atomics) ----------
#define RED_BLOCKS 100
__global__ __launch_bounds__(256) void k_reduce(
    const float* __restrict__ parts, double* __restrict__ stats)
{
    double s = 0.0, ss = 0.0;
    for (int i = blockIdx.x * 256 + threadIdx.x; i < N_NODES; i += RED_BLOCKS * 256) {
        s  += (double)parts[i * 2 + 0];
        ss += (double)parts[i * 2 + 1];
    }
#pragma unroll
    for (int off = 32; off > 0; off >>= 1) {
        s  += __shfl_down(s, off);
        ss += __shfl_down(ss, off);
    }
    __shared__ double sdd[8];
    int wave = threadIdx.x >> 6;
    if ((threadIdx.x & 63) == 0) { sdd[wave * 2] = s; sdd[wave * 2 + 1] = ss; }
    __syncthreads();
    if (threadIdx.x == 0) {
        double S = 0.0, SS = 0.0;
        for (int w = 0; w < 4; w++) { S += sdd[w * 2]; SS += sdd[w * 2 + 1]; }
        atomicAdd(&stats[0], S);
        atomicAdd(&stats[1], SS);
    }
}

// ---------------- graph layernorm + gamma/beta (in-place on d_out, float4) --------
__global__ __launch_bounds__(256) void k_norm(
    float* __restrict__ out, const double* __restrict__ stats,
    const float* __restrict__ gamma, const float* __restrict__ beta)
{
    int i = blockIdx.x * 256 + threadIdx.x;
    if (i >= N_NODES * DIM / 4) return;
    const double cnt = (double)N_NODES * (double)DIM;
    double mean = stats[0] / cnt;
    double var  = stats[1] / cnt - mean * mean;
    if (var < 0.0) var = 0.0;
    float mf = (float)mean;
    float inv = 1.0f / ((float)sqrt(var) + 1e-5f);
    float4 v = ((const float4*)out)[i];
    float4 gv = ((const float4*)gamma)[i & 15];
    float4 bv2 = ((const float4*)beta)[i & 15];
    v.x = (v.x - mf) * inv * gv.x + bv2.x;
    v.y = (v.y - mf) * inv * gv.y + bv2.y;
    v.z = (v.z - mf) * inv * gv.z + bv2.z;
    v.w = (v.w - mf) * inv * gv.w + bv2.w;
    ((float4*)out)[i] = v;
}

extern "C" void kernel_launch(void* const* d_in, const int* in_sizes, int n_in,
                              void* d_out, int out_size, void* d_ws, size_t ws_size,
                              hipStream_t stream) {
    const float* x     = (const float*)d_in[0];
    const int*   ei    = (const int*)d_in[1];
    const float* Wq    = (const float*)d_in[2];
    const float* bq    = (const float*)d_in[3];
    const float* Wk    = (const float*)d_in[4];
    const float* bk    = (const float*)d_in[5];
    const float* Wv    = (const float*)d_in[6];
    const float* bv    = (const float*)d_in[7];
    const float* Wsk   = (const float*)d_in[8];
    const float* bsk   = (const float*)d_in[9];
    const float* Wc    = (const float*)d_in[10];
    const float* bc    = (const float*)d_in[11];
    const float* gamma = (const float*)d_in[12];
    const float* beta  = (const float*)d_in[13];
    float* out = (float*)d_out;

    // ws layout
    float* ws = (float*)d_ws;
    const size_t NF = (size_t)N_NODES * HD;               // 6.4M floats
    float* q = ws;                                        // [N,128] f32
    unsigned short* kv = (unsigned short*)(ws + NF);      // [N,256] bf16 (k|vc)
    float* skipc = ws + 2 * NF;                           // [N,64]  f32
    unsigned short* xb = (unsigned short*)(skipc + (size_t)N_NODES * DIM); // [NPAD,64]
    unsigned short* WallT = xb + (size_t)NPAD * 64;       // [448,64] bf16
    float* ball   = (float*)(WallT + NCOL * 64);          // [448]
    int* deg      = (int*)(ball + NCOL);                  // [N]
    int* rowstart = deg + N_NODES;                        // [N]
    int* bsum     = rowstart + N_NODES;                   // [256]
    int* rank     = bsum + 256;                           // [E]
    int* elist    = rank + N_EDGES;                       // [E]
    float* parts  = (float*)(elist + N_EDGES);            // [N,2]
    double* stats = (double*)(parts + (size_t)N_NODES * 2);

    hipMemsetAsync(deg, 0, N_NODES * sizeof(int), stream);
    hipLaunchKernelGGL(k_pc, dim3(PREP_B + CAST_B), dim3(256), 0, stream,
                       x, ei, Wq, bq, Wk, bk, Wv, bv, Wsk, bsk, Wc, bc,
                       WallT, ball, xb, deg, rank, stats);
    hipLaunchKernelGGL(k_scanA, dim3(SCAN_B), dim3(256), 0, stream, deg, bsum);
    hipLaunchKernelGGL(k_scanB, dim3(SCAN_B), dim3(256), 0, stream, deg, bsum, rowstart);
    hipLaunchKernelGGL(k_fp, dim3(PROJ_B + FILL_B), dim3(256), 0, stream,
                       xb, WallT, ball, q, kv, skipc, ei, rowstart, rank, elist);
    hipLaunchKernelGGL(k_attn, dim3(N_NODES / 4), dim3(256), 0, stream,
                       q, kv, skipc, rowstart, deg, elist, out, parts);
    hipLaunchKernelGGL(k_reduce, dim3(RED_BLOCKS), dim3(256), 0, stream, parts, stats);
    hipLaunchKernelGGL(k_norm, dim3(N_NODES * DIM / 4 / 256 + 1), dim3(256), 0, stream,
                       out, stats, gamma, beta);
}